// Round 5
// baseline (116.121 us; speedup 1.0000x reference)
//
#include <hip/hip_runtime.h>
#include <hip/hip_bf16.h>

// SparseAttentionHead on MI355X — v5: v4's LDS-staged pipeline at BM=16 with
// 2 blocks/CU (74KB LDS each) so one block's barrier-drain overlaps the
// other's compute/issue.
// out[i,c] = elu( sum_j P[i,j]*F[j,c] / Z[i] ),
//   P[i,j] = exp( adj[i,j]*lrelu(a1[i]+a2[j]) ), Z[i] = sum_j P[i,j].

typedef short bf16x8 __attribute__((ext_vector_type(8)));
typedef float f32x4 __attribute__((ext_vector_type(4)));

static __device__ __forceinline__ short f2bf(float f) {
  union { float f; unsigned u; } v; v.f = f;
  unsigned r = v.u + 0x7fffu + ((v.u >> 16) & 1u);
  return (short)(r >> 16);
}

static __device__ __forceinline__ void gld16(const short* g, short* l) {
  __builtin_amdgcn_global_load_lds(
      (const __attribute__((address_space(1))) void*)g,
      (__attribute__((address_space(3))) void*)l, 16, 0, 0);
}

// K1: seq_fts = W1 @ x (fp32), store FT[c][n] = bf16, accumulate a1/a2.
__global__ __launch_bounds__(256) void k1_seqfts(
    const float* __restrict__ x, const float* __restrict__ W1,
    const float* __restrict__ wf1, const float* __restrict__ wf2,
    short* __restrict__ FT, float* __restrict__ a1, float* __restrict__ a2) {
  const int cb = blockIdx.x & 7;
  const int nb = blockIdx.x >> 3;
  const int n = nb * 256 + threadIdx.x;
  float acc[16];
#pragma unroll
  for (int i = 0; i < 16; ++i) acc[i] = 0.f;
  const float* wrow = W1 + cb * 16 * 128;
#pragma unroll 4
  for (int c = 0; c < 128; ++c) {
    float xv = x[c * 8192 + n];
#pragma unroll
    for (int cc = 0; cc < 16; ++cc) acc[cc] = fmaf(wrow[cc * 128 + c], xv, acc[cc]);
  }
  float p1 = 0.f, p2 = 0.f;
#pragma unroll
  for (int cc = 0; cc < 16; ++cc) {
    int co = cb * 16 + cc;
    FT[co * 8192 + n] = f2bf(acc[cc]);
    p1 = fmaf(wf1[co], acc[cc], p1);
    p2 = fmaf(wf2[co], acc[cc], p2);
  }
  atomicAdd(&a1[n], p1);
  atomicAdd(&a2[n], p2);
}

// K2: BM=16 rows/block, BK=128. grid 512, 512 thr (8 waves), 2 blocks/CU.
// Wave w -> output cols [16w, 16w+16), 1 accumulator, 4 MFMA/step.
__global__ __launch_bounds__(512, 4) void k2_attn(
    const float* __restrict__ adj, const short* __restrict__ FT,
    const float* __restrict__ a1, const float* __restrict__ a2,
    const float* __restrict__ b1p, const float* __restrict__ b2p,
    float* __restrict__ out) {
  // P: 16 rows x 128 k bf16, row stride 136 shorts (272B).
  __shared__ __align__(16) short Pl[2][16 * 136];
  // FT: 128 c-rows x 128 k bf16, XOR-swizzled storage (same scheme as v4).
  __shared__ __align__(16) short Ftl[2][16384];
  __shared__ float zl[16];

  const int t = threadIdx.x;
  const int l = t & 63;
  const int w = t >> 6;
  const int r = l & 15;
  const int kg = l >> 4;
  const int i0 = blockIdx.x * 16;

  // ---- P producer: thread t -> row t>>5, k-cols (t&31)*4 .. +4 ----
  const int prow = t >> 5;
  const int pcg = t & 31;
  const float af = a1[i0 + prow] + b1p[0] + b2p[0];
  const float* adjp = adj + (size_t)(i0 + prow) * 8192 + pcg * 4;
  const float* a2p = a2 + pcg * 4;

  // ---- FT staging: instr i covers c = i*32 + w*4 + kg; lane r = 16B k-chunk;
  //      global source pre-swizzled by +8*(r ^ (c&15)); LDS dest linear. ----
  const int swz = 8 * (r ^ ((w * 4 + kg) & 15));
  const short* fsrc0 = FT + (size_t)(0 + w * 4 + kg) * 8192 + swz;
  const short* fsrc1 = FT + (size_t)(32 + w * 4 + kg) * 8192 + swz;
  const short* fsrc2 = FT + (size_t)(64 + w * 4 + kg) * 8192 + swz;
  const short* fsrc3 = FT + (size_t)(96 + w * 4 + kg) * 8192 + swz;

  // ---- MFMA mapping: wave w -> cols [16w, 16w+16) ----
  const int c0 = w * 16 + r;

  f32x4 acc = {0.f, 0.f, 0.f, 0.f};
  float zacc = 0.f;

  auto build = [&](int buf, const f32x4& A, const f32x4& Q) {
    ushort4 pv;
    float tt, lr, p;
    tt = af + Q[0]; lr = fmaxf(tt, 0.01f * tt); p = __expf(A[0] * lr);
    zacc += p; pv.x = (unsigned short)f2bf(p);
    tt = af + Q[1]; lr = fmaxf(tt, 0.01f * tt); p = __expf(A[1] * lr);
    zacc += p; pv.y = (unsigned short)f2bf(p);
    tt = af + Q[2]; lr = fmaxf(tt, 0.01f * tt); p = __expf(A[2] * lr);
    zacc += p; pv.z = (unsigned short)f2bf(p);
    tt = af + Q[3]; lr = fmaxf(tt, 0.01f * tt); p = __expf(A[3] * lr);
    zacc += p; pv.w = (unsigned short)f2bf(p);
    *(ushort4*)&Pl[buf][prow * 136 + pcg * 4] = pv;
  };

  auto compute = [&](int cur) {
    const short* pb = &Pl[cur][r * 136 + kg * 8];
    const short* fb = &Ftl[cur][c0 * 128];
#pragma unroll
    for (int kt = 0; kt < 4; ++kt) {
      bf16x8 Af = *(const bf16x8*)(pb + kt * 32);
      bf16x8 Bf = *(const bf16x8*)(fb + ((kg * 8 + kt * 32) ^ (r * 8)));
      acc = __builtin_amdgcn_mfma_f32_16x16x32_bf16(Af, Bf, acc, 0, 0, 0);
    }
  };

  auto body = [&](int s, const f32x4& uA, const f32x4& uQ, f32x4& fA, f32x4& fQ) {
    const int cur = s & 1, nxt = cur ^ 1;
    if (s + 1 < 64) {                       // stage FT(s+1) -> Ftl[nxt]
      const int kb1 = (s + 1) * 128;
      short* fb = &Ftl[nxt][w * 512];
      gld16(fsrc0 + kb1, fb);
      gld16(fsrc1 + kb1, fb + 4096);
      gld16(fsrc2 + kb1, fb + 8192);
      gld16(fsrc3 + kb1, fb + 12288);
    }
    if (s + 2 < 64) {                       // issue adj/a2(s+2) -> regs
      const int kb2 = (s + 2) * 128;
      fA = *(const f32x4*)(adjp + kb2);
      fQ = *(const f32x4*)(a2p + kb2);
    }
    if (s + 1 < 64) build(nxt, uA, uQ);     // P(s+1) from regs loaded at s-1
    compute(cur);                           // MFMA step s from LDS
    __syncthreads();                        // drain + buffer swap
  };

  // ---- prologue ----
  {
    short* fb = &Ftl[0][w * 512];
    gld16(fsrc0, fb);
    gld16(fsrc1, fb + 4096);
    gld16(fsrc2, fb + 8192);
    gld16(fsrc3, fb + 12288);
  }
  f32x4 tA = *(const f32x4*)(adjp);
  f32x4 tQ = *(const f32x4*)(a2p);
  f32x4 oA = *(const f32x4*)(adjp + 128);
  f32x4 oQ = *(const f32x4*)(a2p + 128);
  f32x4 eA = {0, 0, 0, 0}, eQ = {0, 0, 0, 0};
  build(0, tA, tQ);                         // P(0)
  __syncthreads();                          // P(0)+FT(0) ready

  for (int s = 0; s < 64; s += 2) {
    body(s, oA, oQ, eA, eQ);                // consume adj(s+1), fetch adj(s+2)
    body(s + 1, eA, eQ, oA, oQ);            // consume adj(s+2), fetch adj(s+3)
  }

  // ---- Z: 32 threads per row (half-wave) ----
  float zr = zacc;
  zr += __shfl_down(zr, 16, 32);
  zr += __shfl_down(zr, 8, 32);
  zr += __shfl_down(zr, 4, 32);
  zr += __shfl_down(zr, 2, 32);
  zr += __shfl_down(zr, 1, 32);
  if (pcg == 0) zl[prow] = zr;
  __syncthreads();

  // ---- epilogue: C/D layout col = l&15, row = 4*(l>>4)+q ----
#pragma unroll
  for (int q = 0; q < 4; ++q) {
    const int row = kg * 4 + q;
    const float inv = 1.0f / zl[row];
    float v = acc[q] * inv;
    v = v > 0.f ? v : __expf(v) - 1.f;
    out[(size_t)(i0 + row) * 128 + c0] = v;
  }
}

extern "C" void kernel_launch(void* const* d_in, const int* in_sizes, int n_in,
                              void* d_out, int out_size, void* d_ws, size_t ws_size,
                              hipStream_t stream) {
  const float* x   = (const float*)d_in[0];
  // d_in[1] = edge_index (unused by the reference computation)
  const float* adj = (const float*)d_in[2];
  const float* W1  = (const float*)d_in[3];
  const float* wf1 = (const float*)d_in[4];
  const float* b1  = (const float*)d_in[5];
  const float* wf2 = (const float*)d_in[6];
  const float* b2  = (const float*)d_in[7];
  float* out = (float*)d_out;

  short* FT = (short*)d_ws;                                    // 128*8192 bf16 = 2MB
  float* a1 = (float*)((char*)d_ws + (size_t)2 * 1024 * 1024); // 8192 f32
  float* a2 = a1 + 8192;                                       // 8192 f32

  hipMemsetAsync(a1, 0, 2 * 8192 * sizeof(float), stream);
  k1_seqfts<<<256, 256, 0, stream>>>(x, W1, wf1, wf2, FT, a1, a2);
  k2_attn<<<512, 512, 0, stream>>>(adj, FT, a1, a2, b1, b2, out);
}